// Round 1
// baseline (116.338 us; speedup 1.0000x reference)
//
#include <hip/hip_runtime.h>

#define S_LEN 1024
#define D_DIM 64
#define NPOS 64

__device__ __forceinline__ float sigmoid_fast(float x) {
    // 1 / (1 + e^-x); rcp is ~1ulp, fine vs 1.5e-2 threshold
    return __builtin_amdgcn_rcpf(1.0f + __expf(-x));
}

__device__ __forceinline__ float interp_pos(float pos, const float* __restrict__ logits) {
    pos = fminf(pos, 63.0f);
    float pf = floorf(pos);
    float w  = pos - pf;
    int fi = (int)pf;
    int ci = (int)ceilf(pos);
    return logits[ci] * w + logits[fi] * (1.0f - w);
}

__global__ __launch_bounds__(256) void cope_kernel(
    const float* __restrict__ attn,
    const float* __restrict__ query,
    const float* __restrict__ pe,     // [D_DIM][NPOS]
    float* __restrict__ out)
{
    __shared__ float lds_q[D_DIM];
    __shared__ float lds_logits[NPOS];
    __shared__ float lds_wsum[4];

    const int row  = blockIdx.x;           // (b*H + h)*S + s
    const int t    = threadIdx.x;          // 256 threads, 4 elems each
    const int lane = t & 63;
    const int wid  = t >> 6;

    // stage query row (64 floats) for the mini-GEMV
    if (t < D_DIM) lds_q[t] = query[(size_t)row * D_DIM + t];
    __syncthreads();

    // logits_int[n] = sum_d q[d] * pe[d][n]  (pos_emb is 16KB, L2-resident)
    if (t < NPOS) {
        float acc = 0.f;
        #pragma unroll
        for (int d = 0; d < D_DIM; ++d)
            acc = fmaf(lds_q[d], pe[d * NPOS + t], acc);
        lds_logits[t] = acc;
    }

    // load 4 contiguous gates per thread (float4, fully coalesced)
    const float4* in4 = reinterpret_cast<const float4*>(attn) + (size_t)row * (S_LEN / 4);
    float4 xv = in4[t];
    float g0 = sigmoid_fast(xv.x);
    float g1 = sigmoid_fast(xv.y);
    float g2 = sigmoid_fast(xv.z);
    float g3 = sigmoid_fast(xv.w);
    float s  = (g0 + g1) + (g2 + g3);

    // wave-level inclusive SUFFIX scan of per-thread sums
    float v = s;
    #pragma unroll
    for (int off = 1; off < 64; off <<= 1) {
        float o = __shfl_down(v, off, 64);
        if (lane + off < 64) v += o;
    }
    if (lane == 0) lds_wsum[wid] = v;   // lane 0 holds whole-wave sum
    __syncthreads();                    // also publishes lds_logits

    // add totals of later waves -> global suffix-inclusive; subtract own s -> exclusive
    float wtail = 0.f;
    #pragma unroll
    for (int w = 0; w < 4; ++w)
        if (w > wid) wtail += lds_wsum[w];
    float excl = (v + wtail) - s;       // sum of all gates after this thread's chunk

    // per-thread reversed running sum over its 4 elements
    float p3 = g3 + excl;
    float p2 = g2 + p3;
    float p1 = g1 + p2;
    float p0 = g0 + p1;

    float4 o;
    o.x = interp_pos(p0, lds_logits);
    o.y = interp_pos(p1, lds_logits);
    o.z = interp_pos(p2, lds_logits);
    o.w = interp_pos(p3, lds_logits);

    float4* out4 = reinterpret_cast<float4*>(out) + (size_t)row * (S_LEN / 4);
    out4[t] = o;
}

extern "C" void kernel_launch(void* const* d_in, const int* in_sizes, int n_in,
                              void* d_out, int out_size, void* d_ws, size_t ws_size,
                              hipStream_t stream) {
    const float* attn  = (const float*)d_in[0];   // [B,H,S,S] f32
    const float* query = (const float*)d_in[1];   // [B,H,S,D] f32
    const float* pe    = (const float*)d_in[2];   // [1,D,NPOS] f32
    float* out = (float*)d_out;                   // [B,H,S,S] f32

    const int rows = in_sizes[0] / S_LEN;         // B*H*S = 49152
    cope_kernel<<<rows, 256, 0, stream>>>(attn, query, pe, out);
}

// Round 2
// 82.499 us; speedup vs baseline: 1.4102x; 1.4102x over previous
//
#include <hip/hip_runtime.h>

#define S_LEN 1024
#define D_DIM 64
#define NPOS 64
#define NBLOCKS 3072   // 12288 waves -> 4 rows/wave at 49152 rows

__device__ __forceinline__ float sigmoid_fast(float x) {
    return __builtin_amdgcn_rcpf(1.0f + __expf(-x));
}

__device__ __forceinline__ float interp_pos(float p, float lreg) {
    p = fminf(p, 63.0f);
    float pf = floorf(p);
    float w  = p - pf;
    int   fi = (int)pf;
    int   ci = (int)ceilf(p);
    float lf = __shfl(lreg, fi, 64);   // ds_bpermute gather from wave registers
    float lc = __shfl(lreg, ci, 64);
    return lc * w + lf * (1.0f - w);
}

__global__ __launch_bounds__(256) void cope_kernel(
    const float* __restrict__ attn,
    const float* __restrict__ query,
    const float* __restrict__ pe,     // [D_DIM][NPOS]
    float* __restrict__ out,
    int nrows)
{
    const int lane   = threadIdx.x & 63;
    const int gwave  = blockIdx.x * 4 + (threadIdx.x >> 6);
    const int nwaves = gridDim.x * 4;

    for (int row = gwave; row < nrows; row += nwaves) {
        // row is wave-uniform; force SGPR addressing (enables s_load of query row)
        const int urow = __builtin_amdgcn_readfirstlane(row);

        // issue the 4 coalesced attn loads first (1 KB per instruction per wave)
        const float* arow = attn + (size_t)urow * S_LEN;
        float4 xv[4];
        #pragma unroll
        for (int k = 0; k < 4; ++k)
            xv[k] = *reinterpret_cast<const float4*>(arow + k * 256 + 4 * lane);

        // GEMV while attn loads are in flight:
        // logits[lane] = sum_d q[d] * pe[d][lane]; q via scalar loads (uniform),
        // pe is 16KB -> L1-resident after warmup.
        const float* qrow = query + (size_t)urow * D_DIM;
        float lreg = 0.f;
        #pragma unroll
        for (int d = 0; d < D_DIM; ++d)
            lreg = fmaf(qrow[d], pe[d * NPOS + lane], lreg);

        // sigmoid + per-lane section sums (section k = elements [256k, 256k+256))
        float s[4], I[4];
        #pragma unroll
        for (int k = 0; k < 4; ++k) {
            xv[k].x = sigmoid_fast(xv[k].x);
            xv[k].y = sigmoid_fast(xv[k].y);
            xv[k].z = sigmoid_fast(xv[k].z);
            xv[k].w = sigmoid_fast(xv[k].w);
            s[k] = (xv[k].x + xv[k].y) + (xv[k].z + xv[k].w);
        }

        // in-wave inclusive SUFFIX scans (Kogge-Stone, 6 steps each)
        #pragma unroll
        for (int k = 0; k < 4; ++k) {
            float v = s[k];
            #pragma unroll
            for (int off = 1; off < 64; off <<= 1) {
                float o = __shfl_down(v, off, 64);
                if (lane + off < 64) v += o;
            }
            I[k] = v;
        }

        // section totals + tails (sum of gates in later sections)
        float T1 = __shfl(I[1], 0, 64);
        float T2 = __shfl(I[2], 0, 64);
        float T3 = __shfl(I[3], 0, 64);
        float tail[4] = { T1 + T2 + T3, T2 + T3, T3, 0.f };

        float* orow = out + (size_t)urow * S_LEN;
        #pragma unroll
        for (int k = 0; k < 4; ++k) {
            float after = (I[k] - s[k]) + tail[k];   // gates strictly after this lane's chunk
            float p3 = xv[k].w + after;
            float p2 = xv[k].z + p3;
            float p1 = xv[k].y + p2;
            float p0 = xv[k].x + p1;
            float4 o;
            o.x = interp_pos(p0, lreg);
            o.y = interp_pos(p1, lreg);
            o.z = interp_pos(p2, lreg);
            o.w = interp_pos(p3, lreg);
            *reinterpret_cast<float4*>(orow + k * 256 + 4 * lane) = o;
        }
    }
}

extern "C" void kernel_launch(void* const* d_in, const int* in_sizes, int n_in,
                              void* d_out, int out_size, void* d_ws, size_t ws_size,
                              hipStream_t stream) {
    const float* attn  = (const float*)d_in[0];   // [B,H,S,S] f32
    const float* query = (const float*)d_in[1];   // [B,H,S,D] f32
    const float* pe    = (const float*)d_in[2];   // [1,D,NPOS] f32
    float* out = (float*)d_out;                   // [B,H,S,S] f32

    const int rows = in_sizes[0] / S_LEN;         // B*H*S = 49152
    cope_kernel<<<NBLOCKS, 256, 0, stream>>>(attn, query, pe, out, rows);
}